// Round 5
// baseline (367.160 us; speedup 1.0000x reference)
//
#include <hip/hip_runtime.h>
#include <cstdint>
#include <climits>

#pragma clang fp contract(off)

#define N_PTS 8192
#define B_SZ  4
#define K_NN  20
#define O_CH  64
#define QW    64              // queries per block (= lanes per wave)
#define NSW   7               // scanning waves (1..7); wave 0 = drain wave
#define SUBL  1170            // subset length per scan wave (wave 7 gets 1172)
#define WARM  96              // warm-up candidates per scan thread (values-only)
#define CAP   8               // survivor stack capacity per thread per chunk
#define SPAD  9               // stack row stride (u64)
#define NCH   6               // chunks per subset

typedef unsigned long long u64k;

// pd = -xx_n - (-2*dot) - xx_m with numpy rounding order.
// fma(dot,2,-xxn): 2*dot is exact => identical bits to round(2dot - xxn).
__device__ __forceinline__ float pd_np(float qx, float qy, float qz, float xxn,
                                       float cx, float cy, float cz, float xm) {
  float p0 = qx * cx;
  float p1 = qy * cy;
  float p2 = qz * cz;
  float dot = (p0 + p1) + p2;
  float t = __builtin_fmaf(dot, 2.0f, -xxn);
  return t - xm;
}

// values-only gated branchless sorted insert (ascending; keeps 20 largest)
__device__ __forceinline__ void insert20(float (&arr)[K_NN], float v) {
  float c = v;
#pragma unroll
  for (int u = K_NN - 1; u >= 0; --u) {
    float hi = fmaxf(arr[u], c);
    c = fminf(arr[u], c);
    arr[u] = hi;
  }
}

// packed-key sorted insert: key = (sortable_pd << 13) | (8191 - j)
// u64 descending == (pd desc, j asc) == jax.lax.top_k order (set semantics).
__device__ __forceinline__ void insK(u64k (&a)[K_NN], u64k k) {
  u64k c = k;
#pragma unroll
  for (int u = K_NN - 1; u >= 0; --u) {
    bool g = a[u] > c;
    u64k hi = g ? a[u] : c;
    u64k lo = g ? c : a[u];
    a[u] = hi;
    c = lo;
  }
}

__device__ __forceinline__ unsigned sortable32(float pd) {
  unsigned s = __float_as_uint(pd);
  return s ^ ((unsigned)((int)s >> 31) | 0x80000000u);
}

__device__ __forceinline__ u64k packKey(float pd, int j) {
  return ((u64k)sortable32(pd) << 13) | (unsigned)(8191 - j);
}

__device__ __forceinline__ float keyPd(u64k k) {
  unsigned sp = (unsigned)(k >> 13);
  unsigned s = (sp & 0x80000000u) ? (sp & 0x7FFFFFFFu) : ~sp;
  return __uint_as_float(s);
}

__global__ __launch_bounds__(256, 2)
void pack_kernel(const float* __restrict__ x, float4* __restrict__ P) {
  int idx = blockIdx.x * 256 + threadIdx.x;   // b*N + n
  if (idx >= B_SZ * N_PTS) return;
  int b = idx >> 13;
  int n = idx & (N_PTS - 1);
  const float* xb = x + (size_t)b * 3 * N_PTS;
  float x0 = xb[n];
  float x1 = xb[n + N_PTS];
  float x2 = xb[n + 2 * N_PTS];
  float xxv = (x0 * x0 + x1 * x1) + x2 * x2;  // numpy order, no contraction
  P[idx] = make_float4(x0, x1, x2, xxv);
}

__global__ __launch_bounds__(512, 4)
void knn_edgeconv_kernel(const float4* __restrict__ P,
                         const float* __restrict__ W,
                         const float* __restrict__ bias,
                         float* __restrict__ out) {
  __shared__ u64k  stk[2 * NSW * 64 * SPAD];   // double-buffered stacks (also warm scratch)
  __shared__ int   cnt2[2][NSW * 64];
  __shared__ short of2[2][NSW * 64];
  __shared__ float tau_l[QW];
  __shared__ int   list_l[QW][21];

  const int t  = threadIdx.x;
  const int ql = t & 63;
  const int s  = t >> 6;              // wave id: 0 = drain, 1..7 = scan
  const int wb = blockIdx.x;          // 0..511
  const int b  = wb >> 7;
  const int n0 = (wb & 127) << 6;
  const int q  = n0 + ql;

  // opaque zero: forces candidate addresses into VGPRs -> global_load (vmcnt
  // pipelining) instead of scalarized s_load (lgkmcnt(0) full-drain stalls).
  int vz;
  asm volatile("v_mov_b32 %0, 0" : "=v"(vz));

  const float4* __restrict__ Pb = P + (size_t)b * N_PTS;

  const float4 qc = Pb[q];
  const float qx = qc.x, qy = qc.y, qz = qc.z, xxn = qc.w;

  const int sw   = __builtin_amdgcn_readfirstlane(s);
  const int j0   = (sw - 1) * SUBL;            // scan waves only
  const int LEN  = (sw == 7) ? (N_PTS - 6 * SUBL) : SUBL;   // 1172 for wave 7
  const int tid7 = ((sw - 1) << 6) | ql;       // 0..447 for scan waves
  const int CB[NCH + 1] = {0, 96, 192, 320, 512, 800, SUBL};

  // ---- Warm-up (scan waves): values-only top-20 of first WARM own candidates ----
  float arrv[K_NN];
#pragma unroll
  for (int i = 0; i < K_NN; ++i) arrv[i] = -__builtin_inff();
  if (s >= 1) {
#pragma unroll 4
    for (int jj = 0; jj < WARM; ++jj) {
      int j = j0 + jj;
      float4 cd = Pb[j + vz];
      float pd = pd_np(qx, qy, qz, xxn, cd.x, cd.y, cd.z, cd.w);
      if (pd > arrv[0]) insert20(arrv, pd);
    }
    float* WV = (float*)stk;
#pragma unroll
    for (int i = 0; i < K_NN; ++i) WV[tid7 * 21 + i] = arrv[i];
  }
  __syncthreads();

  // ---- Drain wave: merge 7 warm lists -> tau0 = exact 20th of 672-sample ----
  u64k karr[K_NN];
#pragma unroll
  for (int i = 0; i < K_NN; ++i) karr[i] = 0ULL;
  if (s == 0) {
    const float* WV = (const float*)stk;
    for (int p = 0; p < NSW; ++p) {
      const float* pv = WV + ((p << 6) + t) * 21;
      for (int i = 0; i < K_NN; ++i) {
        float v = pv[i];
        if (v > arrv[0]) insert20(arrv, v);
      }
    }
    tau_l[t] = arrv[0];
  }
  __syncthreads();

  // ---- Pipelined stages: scan chunk st (waves 1-7) || drain chunk st-1 (wave 0) ----
#define PUSH(pdv, jv)                                          \
  if ((pdv) >= tau) {                                          \
    if (cnt < CAP) { my[cnt] = packKey((pdv), (jv)); ++cnt; }  \
    else if (ofj < 0) ofj = (jv);                              \
  }

  for (int st = 0; st <= NCH; ++st) {
    if (s >= 1 && st < NCH) {
      const int c = st;
      const float tau = tau_l[ql];
      int cnt = 0, ofj = -1;
      const int jb = j0 + CB[c];
      const int je = j0 + ((c == NCH - 1) ? LEN : CB[c + 1]);
      u64k* my = stk + (size_t)(c & 1) * (NSW * 64 * SPAD) + (size_t)tid7 * SPAD;
      int j = jb;
      for (; j + 7 < je; j += 8) {
        float4 d0 = Pb[j + 0 + vz];
        float4 d1 = Pb[j + 1 + vz];
        float4 d2 = Pb[j + 2 + vz];
        float4 d3 = Pb[j + 3 + vz];
        float4 d4 = Pb[j + 4 + vz];
        float4 d5 = Pb[j + 5 + vz];
        float4 d6 = Pb[j + 6 + vz];
        float4 d7 = Pb[j + 7 + vz];
        float pd0 = pd_np(qx, qy, qz, xxn, d0.x, d0.y, d0.z, d0.w);
        float pd1 = pd_np(qx, qy, qz, xxn, d1.x, d1.y, d1.z, d1.w);
        float pd2 = pd_np(qx, qy, qz, xxn, d2.x, d2.y, d2.z, d2.w);
        float pd3 = pd_np(qx, qy, qz, xxn, d3.x, d3.y, d3.z, d3.w);
        float pd4 = pd_np(qx, qy, qz, xxn, d4.x, d4.y, d4.z, d4.w);
        float pd5 = pd_np(qx, qy, qz, xxn, d5.x, d5.y, d5.z, d5.w);
        float pd6 = pd_np(qx, qy, qz, xxn, d6.x, d6.y, d6.z, d6.w);
        float pd7 = pd_np(qx, qy, qz, xxn, d7.x, d7.y, d7.z, d7.w);
        PUSH(pd0, j + 0)
        PUSH(pd1, j + 1)
        PUSH(pd2, j + 2)
        PUSH(pd3, j + 3)
        PUSH(pd4, j + 4)
        PUSH(pd5, j + 5)
        PUSH(pd6, j + 6)
        PUSH(pd7, j + 7)
      }
      for (; j < je; ++j) {
        float4 d0 = Pb[j + vz];
        float pd0 = pd_np(qx, qy, qz, xxn, d0.x, d0.y, d0.z, d0.w);
        PUSH(pd0, j)
      }
      cnt2[c & 1][tid7] = cnt;
      of2[c & 1][tid7]  = (short)ofj;
    }
    if (s == 0 && st >= 1) {
      const int c = st - 1;
      const float tauc = tau_l[t];
      const u64k* sb = stk + (size_t)(c & 1) * (NSW * 64 * SPAD);
      for (int p = 0; p < NSW; ++p) {
        const int pt = (p << 6) + t;
        int pc = cnt2[c & 1][pt];
        const u64k* ps = sb + (size_t)pt * SPAD;
        for (int i = 0; i < pc; ++i) {
          u64k k = ps[i];
          if (k > karr[0]) insK(karr, k);
        }
      }
      for (int p = 0; p < NSW; ++p) {        // rare: exact overflow rescan
        const int pt = (p << 6) + t;
        int oj = of2[c & 1][pt];
        if (oj >= 0) {
          int je_abs = p * SUBL +
              ((c == NCH - 1) ? ((p == NSW - 1) ? (N_PTS - 6 * SUBL) : SUBL)
                              : CB[c + 1]);
          for (int j = oj; j < je_abs; ++j) {
            float4 cd = Pb[j + vz];
            float pdv = pd_np(qx, qy, qz, xxn, cd.x, cd.y, cd.z, cd.w);
            if (pdv >= tauc) {
              u64k k = packKey(pdv, j);
              if (k > karr[0]) insK(karr, k);
            }
          }
        }
      }
      float t20 = keyPd(karr[0]);            // NaN while karr not full -> fmaxf keeps old
      tau_l[t] = fmaxf(tauc, t20);
    }
    __syncthreads();
  }
#undef PUSH

  // ---- Publish final neighbor indices ----
  if (s == 0) {
#pragma unroll
    for (int i = 0; i < K_NN; ++i)
      list_l[t][i] = 8191 - (int)(karr[i] & 8191ULL);
  }
  __syncthreads();

  // ---- EdgeConv: max_j( W[:,0:3]·(x_m - x_n) ) + center term, leaky relu ----
  float acc[8];
#pragma unroll
  for (int oi = 0; oi < 8; ++oi) acc[oi] = -__builtin_inff();
  const int o0 = s * 8;
  const float* __restrict__ Wp = W + o0 * 6;

  for (int nb = 0; nb < K_NN; ++nb) {
    int m = list_l[ql][nb] & (N_PTS - 1);   // mask: memory-safety belt
    float4 cm = Pb[m];
    float dx = cm.x - qx;
    float dy = cm.y - qy;
    float dz = cm.z - qz;
#pragma unroll
    for (int oi = 0; oi < 8; ++oi) {
      float h = __builtin_fmaf(dz, Wp[oi * 6 + 2],
                __builtin_fmaf(dy, Wp[oi * 6 + 1], dx * Wp[oi * 6 + 0]));
      acc[oi] = fmaxf(acc[oi], h);
    }
  }

#pragma unroll
  for (int oi = 0; oi < 8; ++oi) {
    int o = o0 + oi;
    float base = __builtin_fmaf(qz, Wp[oi * 6 + 5],
                 __builtin_fmaf(qy, Wp[oi * 6 + 4], qx * Wp[oi * 6 + 3])) + bias[o];
    float v = acc[oi] + base;
    v = fmaxf(v, 0.2f * v);                 // leaky_relu (monotone, commutes with max)
    out[((size_t)(b * O_CH + o) << 13) + q] = v;
  }
}

extern "C" void kernel_launch(void* const* d_in, const int* in_sizes, int n_in,
                              void* d_out, int out_size, void* d_ws, size_t ws_size,
                              hipStream_t stream) {
  const float* x    = (const float*)d_in[0];
  const float* W    = (const float*)d_in[1];
  const float* bias = (const float*)d_in[2];
  float4* P  = (float4*)d_ws;               // B*N float4 = 512 KB
  float* out = (float*)d_out;

  pack_kernel<<<dim3((B_SZ * N_PTS + 255) / 256), dim3(256), 0, stream>>>(x, P);
  knn_edgeconv_kernel<<<dim3(B_SZ * (N_PTS / QW)), dim3(512), 0, stream>>>(P, W, bias, out);
}